// Round 1
// baseline (723.143 us; speedup 1.0000x reference)
//
#include <hip/hip_runtime.h>
#include <math.h>

#define BATCH 8
#define LSEQ  1024
#define DM    256
#define DI    512
#define DS    16
#define RK    16
#define KDIR  4
#define CPROJ 48      // RK + 2*DS
#define NC    8       // scan chunks
#define CL    128     // LSEQ / NC

// direction permutation: position in original sequence for step l of direction k
__device__ __forceinline__ int perm_l(int k, int l) {
    const int H = LSEQ / 2;
    if (k == 0) return l;
    if (k == 1) return LSEQ - 1 - l;
    if (k == 2) return (l < H) ? (2 * l) : (2 * (l - H) + 1);   // eo
    return (l < H) ? (2 * l + 1) : (2 * (l - H));               // oe
}

// C[M,N] = A[M,Kd] * B[N,Kd]^T   (all row-major, fp32)
__global__ __launch_bounds__(256) void gemm_tn(
    const float* __restrict__ A, const float* __restrict__ B,
    float* __restrict__ C, int M, int N, int Kd)
{
    __shared__ float As[16][64 + 4];
    __shared__ float Bs[16][64 + 4];
    const int tid = threadIdx.x;
    const int tx = tid & 15, ty = tid >> 4;
    const int row0 = blockIdx.y * 64, col0 = blockIdx.x * 64;
    const int lr = tid >> 2;          // 0..63
    const int lc = (tid & 3) << 2;    // 0,4,8,12
    float acc[4][4] = {};
    for (int k0 = 0; k0 < Kd; k0 += 16) {
        float4 a4 = *(const float4*)(A + (size_t)(row0 + lr) * Kd + (k0 + lc));
        float4 b4 = *(const float4*)(B + (size_t)(col0 + lr) * Kd + (k0 + lc));
        As[lc + 0][lr] = a4.x; As[lc + 1][lr] = a4.y;
        As[lc + 2][lr] = a4.z; As[lc + 3][lr] = a4.w;
        Bs[lc + 0][lr] = b4.x; Bs[lc + 1][lr] = b4.y;
        Bs[lc + 2][lr] = b4.z; Bs[lc + 3][lr] = b4.w;
        __syncthreads();
#pragma unroll
        for (int kk = 0; kk < 16; ++kk) {
            float ar[4], br[4];
#pragma unroll
            for (int i = 0; i < 4; ++i) ar[i] = As[kk][ty * 4 + i];
#pragma unroll
            for (int j = 0; j < 4; ++j) br[j] = Bs[kk][tx * 4 + j];
#pragma unroll
            for (int i = 0; i < 4; ++i)
#pragma unroll
                for (int j = 0; j < 4; ++j) acc[i][j] += ar[i] * br[j];
        }
        __syncthreads();
    }
#pragma unroll
    for (int i = 0; i < 4; ++i) {
        float* Cp = C + (size_t)(row0 + ty * 4 + i) * N + col0 + tx * 4;
#pragma unroll
        for (int j = 0; j < 4; ++j) Cp[j] = acc[i][j];
    }
}

// depthwise causal-ish conv (pad 1 left / 2 right, width 4) + silu
// reads x_ssm = xz[:, :, 0:DI] in (B*L, 2*DI) layout; writes xcl in (B*L, DI)
__global__ __launch_bounds__(256) void conv_silu(
    const float* __restrict__ xz, const float* __restrict__ cw,
    const float* __restrict__ cb, float* __restrict__ xcl)
{
    const int idx = blockIdx.x * 256 + threadIdx.x;   // (b*L + l)*DI + d
    const int d  = idx & (DI - 1);
    const int bl = idx >> 9;
    const int l  = bl & (LSEQ - 1);
    const float w0 = cw[d * 4 + 0], w1 = cw[d * 4 + 1];
    const float w2 = cw[d * 4 + 2], w3 = cw[d * 4 + 3];
    const float* base = xz + (size_t)bl * (2 * DI) + d;
    float acc = cb[d];
    if (l >= 1)        acc += w0 * base[-(2 * DI)];
    acc += w1 * base[0];
    if (l <= LSEQ - 2) acc += w2 * base[2 * DI];
    if (l <= LSEQ - 3) acc += w3 * base[2 * (2 * DI)];
    xcl[idx] = acc / (1.f + expf(-acc));
}

__device__ __forceinline__ float softplusf(float x) {
    return (x > 20.f) ? x : log1pf(expf(x));
}

// pass 1: per-chunk local scan with h0=0; emit decay product P and local end-state S
__global__ __launch_bounds__(512) void scan_pass1(
    const float* __restrict__ xcl, const float* __restrict__ dbl,
    const float* __restrict__ dtw_all, const float* __restrict__ dtb,
    const float* __restrict__ Alogs,
    float* __restrict__ chkP, float* __restrict__ chkS)
{
    const int gid   = blockIdx.x;
    const int chunk = gid & (NC - 1);
    const int k     = (gid / NC) & (KDIR - 1);
    const int b     = gid / (NC * KDIR);
    const int d     = threadIdx.x;
    __shared__ float sm[CPROJ];
    float dtw[RK], A_[DS], h[DS], P[DS];
    const float* wrow = dtw_all + (size_t)(k * DI + d) * RK;
#pragma unroll
    for (int r = 0; r < RK; ++r) dtw[r] = wrow[r];
    const float bias = dtb[k * DI + d];
    const float* arow = Alogs + (size_t)(k * DI + d) * DS;
#pragma unroll
    for (int n = 0; n < DS; ++n) { A_[n] = -expf(arow[n]); h[n] = 0.f; P[n] = 1.f; }

    for (int t = 0; t < CL; ++t) {
        const int l = chunk * CL + t;
        const int p = perm_l(k, l);
        __syncthreads();
        if (d < CPROJ) sm[d] = dbl[(size_t)(b * LSEQ + p) * (KDIR * CPROJ) + k * CPROJ + d];
        __syncthreads();
        const float u = xcl[(size_t)(b * LSEQ + p) * DI + d];
        float dtr = bias;
#pragma unroll
        for (int r = 0; r < RK; ++r) dtr += dtw[r] * sm[r];
        const float delta = softplusf(dtr);
        const float du = delta * u;
#pragma unroll
        for (int n = 0; n < DS; ++n) {
            const float dA = expf(delta * A_[n]);
            P[n] *= dA;
            h[n] = dA * h[n] + du * sm[RK + n];
        }
    }
    float* Pp = chkP + ((size_t)gid * DI + d) * DS;
    float* Sp = chkS + ((size_t)gid * DI + d) * DS;
#pragma unroll
    for (int n = 0; n < DS; ++n) { Pp[n] = P[n]; Sp[n] = h[n]; }
}

// resolve chunk-initial states: h0[c] = P[c-1]*h0[c-1] + S[c-1]
__global__ __launch_bounds__(256) void chunk_combine(
    const float* __restrict__ chkP, const float* __restrict__ chkS,
    float* __restrict__ h0buf)
{
    const int idx = blockIdx.x * 256 + threadIdx.x;   // (b*K+k)*8192 + d*16+n
    const int bk  = idx >> 13;
    const int rem = idx & 8191;
    float h0 = 0.f;
    h0buf[((size_t)bk * NC + 0) * 8192 + rem] = 0.f;
    for (int c = 1; c < NC; ++c) {
        const size_t prev = ((size_t)bk * NC + (c - 1)) * 8192 + rem;
        h0 = chkP[prev] * h0 + chkS[prev];
        h0buf[((size_t)bk * NC + c) * 8192 + rem] = h0;
    }
}

// pass 3: replay chunk scan from true h0, emit y (+ Ds skip term) into original positions
__global__ __launch_bounds__(512) void scan_pass3(
    const float* __restrict__ xcl, const float* __restrict__ dbl,
    const float* __restrict__ dtw_all, const float* __restrict__ dtb,
    const float* __restrict__ Alogs, const float* __restrict__ Dsk,
    const float* __restrict__ h0buf, float* __restrict__ ycomb)
{
    const int gid   = blockIdx.x;
    const int chunk = gid & (NC - 1);
    const int k     = (gid / NC) & (KDIR - 1);
    const int b     = gid / (NC * KDIR);
    const int d     = threadIdx.x;
    __shared__ float sm[CPROJ];
    float dtw[RK], A_[DS], h[DS];
    const float* wrow = dtw_all + (size_t)(k * DI + d) * RK;
#pragma unroll
    for (int r = 0; r < RK; ++r) dtw[r] = wrow[r];
    const float bias = dtb[k * DI + d];
    const float* arow = Alogs + (size_t)(k * DI + d) * DS;
    const float* h0p  = h0buf + ((size_t)gid * DI + d) * DS;
#pragma unroll
    for (int n = 0; n < DS; ++n) { A_[n] = -expf(arow[n]); h[n] = h0p[n]; }
    const float dsv = Dsk[k * DI + d];

    for (int t = 0; t < CL; ++t) {
        const int l = chunk * CL + t;
        const int p = perm_l(k, l);
        __syncthreads();
        if (d < CPROJ) sm[d] = dbl[(size_t)(b * LSEQ + p) * (KDIR * CPROJ) + k * CPROJ + d];
        __syncthreads();
        const float u = xcl[(size_t)(b * LSEQ + p) * DI + d];
        float dtr = bias;
#pragma unroll
        for (int r = 0; r < RK; ++r) dtr += dtw[r] * sm[r];
        const float delta = softplusf(dtr);
        const float du = delta * u;
        float y = dsv * u;
#pragma unroll
        for (int n = 0; n < DS; ++n) {
            const float dA = expf(delta * A_[n]);
            h[n] = dA * h[n] + du * sm[RK + n];
            y += h[n] * sm[2 * RK + n];
        }
        atomicAdd(&ycomb[(size_t)(b * LSEQ + p) * DI + d], y);
    }
}

// LayerNorm over DI + multiply by silu(z); in-place on y
__global__ __launch_bounds__(256) void ln_mul(
    float* __restrict__ y, const float* __restrict__ xz,
    const float* __restrict__ g, const float* __restrict__ bb)
{
    const int row = blockIdx.x;          // b*L + p
    const int tid = threadIdx.x;
    const float y0 = y[(size_t)row * DI + tid];
    const float y1 = y[(size_t)row * DI + 256 + tid];
    __shared__ float s1[256], s2[256];
    s1[tid] = y0 + y1;
    s2[tid] = y0 * y0 + y1 * y1;
    __syncthreads();
    for (int s = 128; s > 0; s >>= 1) {
        if (tid < s) { s1[tid] += s1[tid + s]; s2[tid] += s2[tid + s]; }
        __syncthreads();
    }
    const float mu  = s1[0] * (1.f / DI);
    const float var = s2[0] * (1.f / DI) - mu * mu;
    const float rs  = rsqrtf(var + 1e-5f);
    {
        const int d = tid;
        const float yn = (y0 - mu) * rs * g[d] + bb[d];
        const float z  = xz[(size_t)row * (2 * DI) + DI + d];
        y[(size_t)row * DI + d] = yn * (z / (1.f + expf(-z)));
    }
    {
        const int d = tid + 256;
        const float yn = (y1 - mu) * rs * g[d] + bb[d];
        const float z  = xz[(size_t)row * (2 * DI) + DI + d];
        y[(size_t)row * DI + d] = yn * (z / (1.f + expf(-z)));
    }
}

extern "C" void kernel_launch(void* const* d_in, const int* in_sizes, int n_in,
                              void* d_out, int out_size, void* d_ws, size_t ws_size,
                              hipStream_t stream)
{
    const float* x        = (const float*)d_in[0];
    const float* in_proj  = (const float*)d_in[1];
    const float* conv_w   = (const float*)d_in[2];
    const float* conv_b   = (const float*)d_in[3];
    const float* x_proj   = (const float*)d_in[4];   // (K,48,DI) = (192,512)
    const float* dt_proj  = (const float*)d_in[5];   // (K,DI,RK)
    const float* dt_bias  = (const float*)d_in[6];   // (K,DI)
    const float* A_logs   = (const float*)d_in[7];   // (K,DI,DS)
    const float* Ds       = (const float*)d_in[8];   // (K,DI)
    const float* ln_g     = (const float*)d_in[9];
    const float* ln_b     = (const float*)d_in[10];
    const float* out_proj = (const float*)d_in[11];  // (DM,DI)
    float* out = (float*)d_out;

    const int M = BATCH * LSEQ;                      // 8192
    float* ws    = (float*)d_ws;
    float* xz    = ws;                               // M*1024  (x_ssm | z)
    float* xcl   = xz    + (size_t)M * 1024;         // M*DI    post-conv silu
    float* dbl   = xcl   + (size_t)M * DI;           // M*192   (dt|B|C per k)
    float* ycomb = dbl   + (size_t)M * (KDIR*CPROJ); // M*DI
    float* chkP  = ycomb + (size_t)M * DI;           // 32*NC*DI*DS = 2097152
    float* chkS  = chkP  + (size_t)2097152;
    float* h0b   = chkS  + (size_t)2097152;

    // 1. xz = x @ in_proj^T        (8192 x 1024, K=256)
    gemm_tn<<<dim3(1024 / 64, M / 64), 256, 0, stream>>>(x, in_proj, xz, M, 1024, DM);
    // 2. depthwise conv + silu -> xcl (position-major)
    conv_silu<<<(M * DI) / 256, 256, 0, stream>>>(xz, conv_w, conv_b, xcl);
    // 3. dbl = xcl @ x_proj^T      (8192 x 192, K=512) — all 4 directions at once
    gemm_tn<<<dim3(192 / 64, M / 64), 256, 0, stream>>>(xcl, x_proj, dbl, M, 192, DI);
    // 4. zero the combine buffer
    hipMemsetAsync(ycomb, 0, (size_t)M * DI * sizeof(float), stream);
    // 5-7. chunked selective scan
    scan_pass1<<<BATCH * KDIR * NC, DI, 0, stream>>>(xcl, dbl, dt_proj, dt_bias, A_logs, chkP, chkS);
    chunk_combine<<<(BATCH * KDIR * DI * DS) / 256, 256, 0, stream>>>(chkP, chkS, h0b);
    scan_pass3<<<BATCH * KDIR * NC, DI, 0, stream>>>(xcl, dbl, dt_proj, dt_bias, A_logs, Ds, h0b, ycomb);
    // 8. LayerNorm * silu(z), in place
    ln_mul<<<M, 256, 0, stream>>>(ycomb, xz, ln_g, ln_b);
    // 9. out = yln @ out_proj^T    (8192 x 256, K=512)
    gemm_tn<<<dim3(DM / 64, M / 64), 256, 0, stream>>>(ycomb, out_proj, out, M, DM, DI);
}

// Round 2
// 406.366 us; speedup vs baseline: 1.7795x; 1.7795x over previous
//
#include <hip/hip_runtime.h>
#include <math.h>

#define BATCH 8
#define LSEQ  1024
#define DM    256
#define DI    512
#define DS    16
#define RK    16
#define KDIR  4
#define CPROJ 48      // RK + 2*DS
#define NC    16      // scan chunks
#define CL    64      // LSEQ / NC
#define STG   16      // timesteps staged per barrier window

// direction permutation: position in original sequence for step l of direction k
__device__ __forceinline__ int perm_l(int k, int l) {
    const int H = LSEQ / 2;
    if (k == 0) return l;
    if (k == 1) return LSEQ - 1 - l;
    if (k == 2) return (l < H) ? (2 * l) : (2 * (l - H) + 1);   // eo
    return (l < H) ? (2 * l + 1) : (2 * (l - H));               // oe
}

// C[M,N] = A[M,Kd] * B[N,Kd]^T   (all row-major, fp32)
__global__ __launch_bounds__(256) void gemm_tn(
    const float* __restrict__ A, const float* __restrict__ B,
    float* __restrict__ C, int M, int N, int Kd)
{
    __shared__ float As[16][64 + 4];
    __shared__ float Bs[16][64 + 4];
    const int tid = threadIdx.x;
    const int tx = tid & 15, ty = tid >> 4;
    const int row0 = blockIdx.y * 64, col0 = blockIdx.x * 64;
    const int lr = tid >> 2;          // 0..63
    const int lc = (tid & 3) << 2;    // 0,4,8,12
    float acc[4][4] = {};
    for (int k0 = 0; k0 < Kd; k0 += 16) {
        float4 a4 = *(const float4*)(A + (size_t)(row0 + lr) * Kd + (k0 + lc));
        float4 b4 = *(const float4*)(B + (size_t)(col0 + lr) * Kd + (k0 + lc));
        As[lc + 0][lr] = a4.x; As[lc + 1][lr] = a4.y;
        As[lc + 2][lr] = a4.z; As[lc + 3][lr] = a4.w;
        Bs[lc + 0][lr] = b4.x; Bs[lc + 1][lr] = b4.y;
        Bs[lc + 2][lr] = b4.z; Bs[lc + 3][lr] = b4.w;
        __syncthreads();
#pragma unroll
        for (int kk = 0; kk < 16; ++kk) {
            float ar[4], br[4];
#pragma unroll
            for (int i = 0; i < 4; ++i) ar[i] = As[kk][ty * 4 + i];
#pragma unroll
            for (int j = 0; j < 4; ++j) br[j] = Bs[kk][tx * 4 + j];
#pragma unroll
            for (int i = 0; i < 4; ++i)
#pragma unroll
                for (int j = 0; j < 4; ++j) acc[i][j] += ar[i] * br[j];
        }
        __syncthreads();
    }
#pragma unroll
    for (int i = 0; i < 4; ++i) {
        float* Cp = C + (size_t)(row0 + ty * 4 + i) * N + col0 + tx * 4;
#pragma unroll
        for (int j = 0; j < 4; ++j) Cp[j] = acc[i][j];
    }
}

// depthwise conv (pad 1 left / 2 right, width 4) + silu
__global__ __launch_bounds__(256) void conv_silu(
    const float* __restrict__ xz, const float* __restrict__ cw,
    const float* __restrict__ cb, float* __restrict__ xcl)
{
    const int idx = blockIdx.x * 256 + threadIdx.x;   // (b*L + l)*DI + d
    const int d  = idx & (DI - 1);
    const int bl = idx >> 9;
    const int l  = bl & (LSEQ - 1);
    const float w0 = cw[d * 4 + 0], w1 = cw[d * 4 + 1];
    const float w2 = cw[d * 4 + 2], w3 = cw[d * 4 + 3];
    const float* base = xz + (size_t)bl * (2 * DI) + d;
    float acc = cb[d];
    if (l >= 1)        acc += w0 * base[-(2 * DI)];
    acc += w1 * base[0];
    if (l <= LSEQ - 2) acc += w2 * base[2 * DI];
    if (l <= LSEQ - 3) acc += w3 * base[2 * (2 * DI)];
    xcl[idx] = acc / (1.f + __expf(-acc));
}

__device__ __forceinline__ float softplusf_fast(float x) {
    return (x > 20.f) ? x : __logf(1.f + __expf(x));
}

// pass 1: per-chunk local scan with h0=0; emit decay product P and local end-state S
__global__ __launch_bounds__(512) void scan_pass1(
    const float* __restrict__ xcl, const float* __restrict__ dbl,
    const float* __restrict__ dtw_all, const float* __restrict__ dtb,
    const float* __restrict__ Alogs,
    float* __restrict__ chkP, float* __restrict__ chkS)
{
    const int gid   = blockIdx.x;
    const int chunk = gid & (NC - 1);
    const int k     = (gid / NC) & (KDIR - 1);
    const int b     = gid / (NC * KDIR);
    const int d     = threadIdx.x;
    __shared__ float sm[STG][CPROJ];
    float dtw[RK], A_[DS], h[DS], P[DS];
    const float* wrow = dtw_all + (size_t)(k * DI + d) * RK;
#pragma unroll
    for (int r = 0; r < RK; ++r) dtw[r] = wrow[r];
    const float bias = dtb[k * DI + d];
    const float* arow = Alogs + (size_t)(k * DI + d) * DS;
#pragma unroll
    for (int n = 0; n < DS; ++n) { A_[n] = -__expf(arow[n]); h[n] = 0.f; P[n] = 1.f; }

    for (int w = 0; w < CL; w += STG) {
        const int l0 = chunk * CL + w;
        __syncthreads();
        for (int f = threadIdx.x; f < STG * CPROJ; f += 512) {
            const int t = f / CPROJ, c = f - t * CPROJ;
            const int p = perm_l(k, l0 + t);
            sm[t][c] = dbl[(size_t)(b * LSEQ + p) * (KDIR * CPROJ) + k * CPROJ + c];
        }
        float u_reg[STG];
#pragma unroll
        for (int t = 0; t < STG; ++t) {
            const int p = perm_l(k, l0 + t);
            u_reg[t] = xcl[(size_t)(b * LSEQ + p) * DI + d];
        }
        __syncthreads();
#pragma unroll
        for (int t = 0; t < STG; ++t) {
            float dtr = bias;
#pragma unroll
            for (int r = 0; r < RK; ++r) dtr += dtw[r] * sm[t][r];
            const float delta = softplusf_fast(dtr);
            const float du = delta * u_reg[t];
#pragma unroll
            for (int n = 0; n < DS; ++n) {
                const float dA = __expf(delta * A_[n]);
                P[n] *= dA;
                h[n] = dA * h[n] + du * sm[t][RK + n];
            }
        }
    }
    float* Pp = chkP + ((size_t)gid * DI + d) * DS;
    float* Sp = chkS + ((size_t)gid * DI + d) * DS;
#pragma unroll
    for (int n = 0; n < DS; ++n) { Pp[n] = P[n]; Sp[n] = h[n]; }
}

// resolve chunk-initial states IN-PLACE: chkS[c] := h0 entering chunk c
__global__ __launch_bounds__(256) void chunk_combine(
    const float* __restrict__ chkP, float* __restrict__ chkS)
{
    const int idx = blockIdx.x * 256 + threadIdx.x;   // (b*K+k)*8192 + d*16+n
    const int bk  = idx >> 13;
    const int rem = idx & 8191;
    float h0 = 0.f;
    for (int c = 0; c < NC; ++c) {
        const size_t s = ((size_t)bk * NC + c) * 8192 + rem;
        const float P = chkP[s], S = chkS[s];
        const float nh = P * h0 + S;
        chkS[s] = h0;
        h0 = nh;
    }
}

// pass 3: replay chunk scan from true h0 (in chkS), emit y into original positions
__global__ __launch_bounds__(512) void scan_pass3(
    const float* __restrict__ xcl, const float* __restrict__ dbl,
    const float* __restrict__ dtw_all, const float* __restrict__ dtb,
    const float* __restrict__ Alogs, const float* __restrict__ Dsk,
    const float* __restrict__ h0buf, float* __restrict__ ycomb)
{
    const int gid   = blockIdx.x;
    const int chunk = gid & (NC - 1);
    const int k     = (gid / NC) & (KDIR - 1);
    const int b     = gid / (NC * KDIR);
    const int d     = threadIdx.x;
    __shared__ float sm[STG][CPROJ];
    float dtw[RK], A_[DS], h[DS];
    const float* wrow = dtw_all + (size_t)(k * DI + d) * RK;
#pragma unroll
    for (int r = 0; r < RK; ++r) dtw[r] = wrow[r];
    const float bias = dtb[k * DI + d];
    const float* arow = Alogs + (size_t)(k * DI + d) * DS;
    const float* h0p  = h0buf + ((size_t)gid * DI + d) * DS;
#pragma unroll
    for (int n = 0; n < DS; ++n) { A_[n] = -__expf(arow[n]); h[n] = h0p[n]; }
    const float dsv = Dsk[k * DI + d];

    for (int w = 0; w < CL; w += STG) {
        const int l0 = chunk * CL + w;
        __syncthreads();
        for (int f = threadIdx.x; f < STG * CPROJ; f += 512) {
            const int t = f / CPROJ, c = f - t * CPROJ;
            const int p = perm_l(k, l0 + t);
            sm[t][c] = dbl[(size_t)(b * LSEQ + p) * (KDIR * CPROJ) + k * CPROJ + c];
        }
        float u_reg[STG];
#pragma unroll
        for (int t = 0; t < STG; ++t) {
            const int p = perm_l(k, l0 + t);
            u_reg[t] = xcl[(size_t)(b * LSEQ + p) * DI + d];
        }
        __syncthreads();
#pragma unroll
        for (int t = 0; t < STG; ++t) {
            float dtr = bias;
#pragma unroll
            for (int r = 0; r < RK; ++r) dtr += dtw[r] * sm[t][r];
            const float delta = softplusf_fast(dtr);
            const float du = delta * u_reg[t];
            float y = dsv * u_reg[t];
#pragma unroll
            for (int n = 0; n < DS; ++n) {
                const float dA = __expf(delta * A_[n]);
                h[n] = dA * h[n] + du * sm[t][RK + n];
                y += h[n] * sm[t][2 * RK + n];
            }
            const int p = perm_l(k, l0 + t);
            atomicAdd(&ycomb[(size_t)(b * LSEQ + p) * DI + d], y);
        }
    }
}

// LayerNorm over DI + multiply by silu(z); in-place on y
__global__ __launch_bounds__(256) void ln_mul(
    float* __restrict__ y, const float* __restrict__ xz,
    const float* __restrict__ g, const float* __restrict__ bb)
{
    const int row = blockIdx.x;          // b*L + p
    const int tid = threadIdx.x;
    const float y0 = y[(size_t)row * DI + tid];
    const float y1 = y[(size_t)row * DI + 256 + tid];
    __shared__ float s1[256], s2[256];
    s1[tid] = y0 + y1;
    s2[tid] = y0 * y0 + y1 * y1;
    __syncthreads();
    for (int s = 128; s > 0; s >>= 1) {
        if (tid < s) { s1[tid] += s1[tid + s]; s2[tid] += s2[tid + s]; }
        __syncthreads();
    }
    const float mu  = s1[0] * (1.f / DI);
    const float var = s2[0] * (1.f / DI) - mu * mu;
    const float rs  = rsqrtf(var + 1e-5f);
    {
        const int d = tid;
        const float yn = (y0 - mu) * rs * g[d] + bb[d];
        const float z  = xz[(size_t)row * (2 * DI) + DI + d];
        y[(size_t)row * DI + d] = yn * (z / (1.f + __expf(-z)));
    }
    {
        const int d = tid + 256;
        const float yn = (y1 - mu) * rs * g[d] + bb[d];
        const float z  = xz[(size_t)row * (2 * DI) + DI + d];
        y[(size_t)row * DI + d] = yn * (z / (1.f + __expf(-z)));
    }
}

extern "C" void kernel_launch(void* const* d_in, const int* in_sizes, int n_in,
                              void* d_out, int out_size, void* d_ws, size_t ws_size,
                              hipStream_t stream)
{
    const float* x        = (const float*)d_in[0];
    const float* in_proj  = (const float*)d_in[1];
    const float* conv_w   = (const float*)d_in[2];
    const float* conv_b   = (const float*)d_in[3];
    const float* x_proj   = (const float*)d_in[4];   // (K,48,DI)
    const float* dt_proj  = (const float*)d_in[5];   // (K,DI,RK)
    const float* dt_bias  = (const float*)d_in[6];   // (K,DI)
    const float* A_logs   = (const float*)d_in[7];   // (K,DI,DS)
    const float* Ds       = (const float*)d_in[8];   // (K,DI)
    const float* ln_g     = (const float*)d_in[9];
    const float* ln_b     = (const float*)d_in[10];
    const float* out_proj = (const float*)d_in[11];  // (DM,DI)
    float* out = (float*)d_out;

    const int M = BATCH * LSEQ;                      // 8192
    float* ws    = (float*)d_ws;
    float* xz    = ws;                               // M*1024  (x_ssm | z)
    float* xcl   = xz    + (size_t)M * 1024;         // M*DI    post-conv silu
    float* dbl   = xcl   + (size_t)M * DI;           // M*192   (dt|B|C per k)
    float* ycomb = dbl   + (size_t)M * (KDIR*CPROJ); // M*DI
    float* chkP  = ycomb + (size_t)M * DI;           // B*K*NC*DI*DS = 4194304
    float* chkS  = chkP  + (size_t)BATCH*KDIR*NC*DI*DS; // same size; becomes h0

    // 1. xz = x @ in_proj^T        (8192 x 1024, K=256)
    gemm_tn<<<dim3(1024 / 64, M / 64), 256, 0, stream>>>(x, in_proj, xz, M, 1024, DM);
    // 2. depthwise conv + silu -> xcl
    conv_silu<<<(M * DI) / 256, 256, 0, stream>>>(xz, conv_w, conv_b, xcl);
    // 3. dbl = xcl @ x_proj^T      (8192 x 192, K=512) — all 4 directions at once
    gemm_tn<<<dim3(192 / 64, M / 64), 256, 0, stream>>>(xcl, x_proj, dbl, M, 192, DI);
    // 4. zero the combine buffer
    hipMemsetAsync(ycomb, 0, (size_t)M * DI * sizeof(float), stream);
    // 5-7. chunked selective scan
    scan_pass1<<<BATCH * KDIR * NC, DI, 0, stream>>>(xcl, dbl, dt_proj, dt_bias, A_logs, chkP, chkS);
    chunk_combine<<<(BATCH * KDIR * DI * DS) / 256, 256, 0, stream>>>(chkP, chkS);
    scan_pass3<<<BATCH * KDIR * NC, DI, 0, stream>>>(xcl, dbl, dt_proj, dt_bias, A_logs, Ds, chkS, ycomb);
    // 8. LayerNorm * silu(z), in place
    ln_mul<<<M, 256, 0, stream>>>(ycomb, xz, ln_g, ln_b);
    // 9. out = yln @ out_proj^T    (8192 x 256, K=512)
    gemm_tn<<<dim3(DM / 64, M / 64), 256, 0, stream>>>(ycomb, out_proj, out, M, DM, DI);
}